// Round 9
// baseline (218.850 us; speedup 1.0000x reference)
//
#include <hip/hip_runtime.h>
#include <math.h>

#define LN 8      // layers
#define NRBF 256
#define FD 16
#define OUTD 3
#define KC (-0.72134752044f)   // -0.5 * log2(e)

typedef __attribute__((ext_vector_type(8))) short short8;   // 8 x bf16
typedef __attribute__((ext_vector_type(4))) float floatx4;

__device__ __forceinline__ short f2bf(float f) {
    unsigned u = __builtin_bit_cast(unsigned, f);
    u += 0x7fffu + ((u >> 16) & 1u);          // RNE
    return (short)(u >> 16);
}

// Workspace:
//   PKB: short8[(nt*8+j)*64 + lane]  (128 KB)  B-fragments, lane-ordered:
//        n = nt*16+(lane&15), k = (lane>>4)*8+e, m=k>>1 -> {A, -2*A*C}
//   EPI: float4[nt*128 + j*16 + l]   (32 KB)   {KC*t3prefix, w0, w1, w2}, n=nt*16+l

__global__ __launch_bounds__(256) void prep(
    const float* __restrict__ centers, const float* __restrict__ betas,
    const float* __restrict__ W, short* __restrict__ PKB, float* __restrict__ EPI)
{
    __shared__ float ls[LN * 32];
    int blk = blockIdx.x;
    int tid = threadIdx.x;
    if (blk < 32) {
        int t = blk * 256 + tid;           // 8192 total
        int lane = t & 63;
        int nt   = (t >> 6) & 15;
        int j    = t >> 10;
        int n    = nt * 16 + (lane & 15);
        int kq   = lane >> 4;
        size_t base = ((size_t)(j * NRBF + n)) * FD + kq * 4;
        float4 bq = *(const float4*)(betas + base);
        float4 cq = *(const float4*)(centers + base);
        float a0 = __expf(bq.x), a1 = __expf(bq.y), a2 = __expf(bq.z), a3 = __expf(bq.w);
        short8 v;
        v[0] = f2bf(a0); v[1] = f2bf(-2.0f * a0 * cq.x);
        v[2] = f2bf(a1); v[3] = f2bf(-2.0f * a1 * cq.y);
        v[4] = f2bf(a2); v[5] = f2bf(-2.0f * a2 * cq.z);
        v[6] = f2bf(a3); v[7] = f2bf(-2.0f * a3 * cq.w);
        *((short8*)(PKB + (size_t)((nt * 8 + j) * 64 + lane) * 8)) = v;
    } else {
        int jj = tid >> 5;                  // 0..7
        int nl = tid & 31;
        int n  = (blk - 32) * 32 + nl;
        const float* bp = betas   + ((size_t)(jj * NRBF + n)) * FD;
        const float* cp = centers + ((size_t)(jj * NRBF + n)) * FD;
        float s = 0.f;
#pragma unroll
        for (int q = 0; q < 4; ++q) {
            float4 bq = *(const float4*)(bp + q * 4);
            float4 cq = *(const float4*)(cp + q * 4);
            s = fmaf(__expf(bq.x) * cq.x, cq.x, s);
            s = fmaf(__expf(bq.y) * cq.y, cq.y, s);
            s = fmaf(__expf(bq.z) * cq.z, cq.z, s);
            s = fmaf(__expf(bq.w) * cq.w, cq.w, s);
        }
        ls[jj * 32 + nl] = s;
        __syncthreads();
        float t3 = 0.f;
        for (int j2 = 0; j2 <= jj; ++j2) t3 += ls[j2 * 32 + nl];
        float4 e;
        e.x = KC * t3;
        e.y = W[0 * (LN * NRBF) + jj * NRBF + n];
        e.z = W[1 * (LN * NRBF) + jj * NRBF + n];
        e.w = W[2 * (LN * NRBF) + jj * NRBF + n];
        int nt = n >> 4, l = n & 15;
        ((float4*)EPI)[nt * 128 + jj * 16 + l] = e;
    }
}

// One BLOCK = one 16-sample tile; 4 waves, wave w handles nt = w*4..w*4+3.
// Explicit 3-stage pipeline per nt:
//   LB   - 8 independent 16B loads of B-fragments (in flight during VALU)
//   CHAIN- pure 8-MFMA prefix chain into 8 named floatx4 (no VALU reads inside)
//   VALU - preload 8 EPI float4s, then 32 exp + 128 FMA on saved accs
__global__ __launch_bounds__(256, 3) void rbf_mfma(
    const float* __restrict__ feats, const short* __restrict__ PKB,
    const float* __restrict__ EPI, const float* __restrict__ bias,
    float* __restrict__ out, int B)
{
    __shared__ float red[4][48];

    int tid  = threadIdx.x;
    int lane = tid & 63;
    int w    = tid >> 6;
    int b0   = blockIdx.x * 16;
    int m    = lane & 15;
    int kq   = lane >> 4;

    // A-fragments
    int brow = b0 + m; if (brow >= B) brow = B - 1;
    const float* xrow = feats + (size_t)brow * (LN * FD) + kq * 4;
    short8 afrag[LN];
#pragma unroll
    for (int j = 0; j < LN; ++j) {
        float4 x = *((const float4*)(xrow + j * FD));
        short8 f;
        f[0] = f2bf(x.x * x.x); f[1] = f2bf(x.x);
        f[2] = f2bf(x.y * x.y); f[3] = f2bf(x.y);
        f[4] = f2bf(x.z * x.z); f[5] = f2bf(x.z);
        f[6] = f2bf(x.w * x.w); f[7] = f2bf(x.w);
        afrag[j] = f;
    }

    float oacc[12];
#pragma unroll
    for (int i = 0; i < 12; ++i) oacc[i] = 0.f;

    int nt0 = w * 4;
    const short8* pbase = (const short8*)PKB + lane;   // + (nt*8+j)*64
    const float4* ebase = (const float4*)EPI + m;      // + nt*128 + j*16

    short8 bufA[LN], bufB[LN];
    floatx4 sv[LN];

#define LB(buf, ntv)                                                     \
    do {                                                                 \
        const short8* pb_ = pbase + (size_t)(ntv) * (LN * 64);           \
        _Pragma("unroll")                                                \
        for (int j = 0; j < LN; ++j) (buf)[j] = pb_[j * 64];             \
    } while (0)

#define CHAIN(buf)                                                       \
    do {                                                                 \
        floatx4 a_ = {0.f, 0.f, 0.f, 0.f};                               \
        _Pragma("unroll")                                                \
        for (int j = 0; j < LN; ++j) {                                   \
            a_ = __builtin_amdgcn_mfma_f32_16x16x32_bf16(afrag[j], (buf)[j], a_, 0, 0, 0); \
            sv[j] = a_;                                                  \
        }                                                                \
    } while (0)

#define VALUP(ntv)                                                       \
    do {                                                                 \
        const float4* ep_ = ebase + (size_t)(ntv) * 128;                 \
        float4 ev[LN];                                                   \
        _Pragma("unroll")                                                \
        for (int j = 0; j < LN; ++j) ev[j] = ep_[j * 16];                \
        _Pragma("unroll")                                                \
        for (int j = 0; j < LN; ++j) {                                   \
            _Pragma("unroll")                                            \
            for (int r = 0; r < 4; ++r) {                                \
                float rv = __builtin_amdgcn_exp2f(fmaf(sv[j][r], KC, ev[j].x)); \
                oacc[r * 3 + 0] = fmaf(rv, ev[j].y, oacc[r * 3 + 0]);    \
                oacc[r * 3 + 1] = fmaf(rv, ev[j].z, oacc[r * 3 + 1]);    \
                oacc[r * 3 + 2] = fmaf(rv, ev[j].w, oacc[r * 3 + 2]);    \
            }                                                            \
        }                                                                \
    } while (0)

    LB(bufA, nt0 + 0);
    CHAIN(bufA);
    LB(bufB, nt0 + 1);
    VALUP(nt0 + 0);
    CHAIN(bufB);
    LB(bufA, nt0 + 2);
    VALUP(nt0 + 1);
    CHAIN(bufA);
    LB(bufB, nt0 + 3);
    VALUP(nt0 + 2);
    CHAIN(bufB);
    VALUP(nt0 + 3);

#undef LB
#undef CHAIN
#undef VALUP

    // intra-wave reduce over the 16 n-lanes
#pragma unroll
    for (int i = 0; i < 12; ++i) {
        oacc[i] += __shfl_xor(oacc[i], 1);
        oacc[i] += __shfl_xor(oacc[i], 2);
        oacc[i] += __shfl_xor(oacc[i], 4);
        oacc[i] += __shfl_xor(oacc[i], 8);
    }

    if (m < OUTD) {
#pragma unroll
        for (int r = 0; r < 4; ++r)
            red[w][kq * 12 + r * 3 + m] = oacc[r * 3 + m];
    }
    __syncthreads();

    if (tid < 48) {
        int o = tid % 3;
        int idx = b0 * 3 + tid;
        if (idx < B * 3) {
            float s = red[0][tid] + red[1][tid] + red[2][tid] + red[3][tid] + bias[o];
            out[idx] = s;
        }
    }
}

extern "C" void kernel_launch(void* const* d_in, const int* in_sizes, int n_in,
                              void* d_out, int out_size, void* d_ws, size_t ws_size,
                              hipStream_t stream) {
    // inputs: 0=x (UNUSED by reference), 1=feats, 2=centers, 3=betas, 4=W, 5=b
    const float* feats   = (const float*)d_in[1];
    const float* centers = (const float*)d_in[2];
    const float* betas   = (const float*)d_in[3];
    const float* W       = (const float*)d_in[4];
    const float* bias    = (const float*)d_in[5];
    float* out = (float*)d_out;
    int B = in_sizes[1] / (LN * FD);

    short* PKB = (short*)d_ws;                       // 65536 shorts = 128 KB
    float* EPI = (float*)((char*)d_ws + 65536 * 2);  // 8192 floats = 32 KB

    prep<<<40, 256, 0, stream>>>(centers, betas, W, PKB, EPI);

    int tiles = (B + 15) / 16;
    rbf_mfma<<<tiles, 256, 0, stream>>>(feats, PKB, EPI, bias, out, B);
}

// Round 10
// 197.564 us; speedup vs baseline: 1.1077x; 1.1077x over previous
//
#include <hip/hip_runtime.h>
#include <math.h>

#define LN 8      // layers
#define NRBF 256
#define FD 16
#define OUTD 3
#define KC (-0.72134752044f)   // -0.5 * log2(e)

typedef __attribute__((ext_vector_type(8))) short short8;   // 8 x bf16
typedef __attribute__((ext_vector_type(4))) float floatx4;
typedef __attribute__((ext_vector_type(2))) float floatx2;

__device__ __forceinline__ short f2bf(float f) {
    unsigned u = __builtin_bit_cast(unsigned, f);
    u += 0x7fffu + ((u >> 16) & 1u);          // RNE
    return (short)(u >> 16);
}

// Workspace:
//   PKB: short8[(nt*8+j)*64 + lane]  (128 KB)  B-fragments, lane-ordered:
//        n = nt*16+(lane&15), k = (lane>>4)*8+e, m=k>>1 -> {A, -2*A*C}
//   EPI: float4[nt*128 + j*16 + l]   (32 KB)   {KC*t3prefix, w0, w1, w2}, n=nt*16+l

__global__ __launch_bounds__(256) void prep(
    const float* __restrict__ centers, const float* __restrict__ betas,
    const float* __restrict__ W, short* __restrict__ PKB, float* __restrict__ EPI)
{
    __shared__ float ls[LN * 32];
    int blk = blockIdx.x;
    int tid = threadIdx.x;
    if (blk < 32) {
        int t = blk * 256 + tid;           // 8192 total
        int lane = t & 63;
        int nt   = (t >> 6) & 15;
        int j    = t >> 10;
        int n    = nt * 16 + (lane & 15);
        int kq   = lane >> 4;
        size_t base = ((size_t)(j * NRBF + n)) * FD + kq * 4;
        float4 bq = *(const float4*)(betas + base);
        float4 cq = *(const float4*)(centers + base);
        float a0 = __expf(bq.x), a1 = __expf(bq.y), a2 = __expf(bq.z), a3 = __expf(bq.w);
        short8 v;
        v[0] = f2bf(a0); v[1] = f2bf(-2.0f * a0 * cq.x);
        v[2] = f2bf(a1); v[3] = f2bf(-2.0f * a1 * cq.y);
        v[4] = f2bf(a2); v[5] = f2bf(-2.0f * a2 * cq.z);
        v[6] = f2bf(a3); v[7] = f2bf(-2.0f * a3 * cq.w);
        *((short8*)(PKB + (size_t)((nt * 8 + j) * 64 + lane) * 8)) = v;
    } else {
        int jj = tid >> 5;                  // 0..7
        int nl = tid & 31;
        int n  = (blk - 32) * 32 + nl;
        const float* bp = betas   + ((size_t)(jj * NRBF + n)) * FD;
        const float* cp = centers + ((size_t)(jj * NRBF + n)) * FD;
        float s = 0.f;
#pragma unroll
        for (int q = 0; q < 4; ++q) {
            float4 bq = *(const float4*)(bp + q * 4);
            float4 cq = *(const float4*)(cp + q * 4);
            s = fmaf(__expf(bq.x) * cq.x, cq.x, s);
            s = fmaf(__expf(bq.y) * cq.y, cq.y, s);
            s = fmaf(__expf(bq.z) * cq.z, cq.z, s);
            s = fmaf(__expf(bq.w) * cq.w, cq.w, s);
        }
        ls[jj * 32 + nl] = s;
        __syncthreads();
        float t3 = 0.f;
        for (int j2 = 0; j2 <= jj; ++j2) t3 += ls[j2 * 32 + nl];
        float4 e;
        e.x = KC * t3;
        e.y = W[0 * (LN * NRBF) + jj * NRBF + n];
        e.z = W[1 * (LN * NRBF) + jj * NRBF + n];
        e.w = W[2 * (LN * NRBF) + jj * NRBF + n];
        int nt = n >> 4, l = n & 15;
        ((float4*)EPI)[nt * 128 + jj * 16 + l] = e;
    }
}

// One WAVE = one 16-sample tile, all 16 nt, processed as FOUR independent
// chains (nt, nt+4, nt+8, nt+12) interleaved per j-step. Lean-SSA form
// (no local arrays beyond static-unrolled) to stay off the spill cliff.
__global__ __launch_bounds__(256, 4) void rbf_mfma(
    const float* __restrict__ feats, const short* __restrict__ PKB,
    const float* __restrict__ EPI, const float* __restrict__ bias,
    float* __restrict__ out, int B)
{
    int tid  = threadIdx.x;
    int lane = tid & 63;
    int wid  = tid >> 6;
    int ntile_total = (B + 15) >> 4;
    int tile = blockIdx.x * 4 + wid;
    bool tvalid = (tile < ntile_total);
    if (!tvalid) tile = ntile_total - 1;
    int b0 = tile * 16;
    int m  = lane & 15;
    int kq = lane >> 4;

    // A-fragments: lane holds sample b0+m, k-range kq*8.. of each layer
    int brow = b0 + m; if (brow >= B) brow = B - 1;
    const float* xrow = feats + (size_t)brow * (LN * FD) + kq * 4;
    short8 afrag[LN];
#pragma unroll
    for (int j = 0; j < LN; ++j) {
        float4 x = *((const float4*)(xrow + j * FD));
        short8 f;
        f[0] = f2bf(x.x * x.x); f[1] = f2bf(x.x);
        f[2] = f2bf(x.y * x.y); f[3] = f2bf(x.y);
        f[4] = f2bf(x.z * x.z); f[5] = f2bf(x.z);
        f[6] = f2bf(x.w * x.w); f[7] = f2bf(x.w);
        afrag[j] = f;
    }

    floatx2 o01[4];
    float   o2[4];
#pragma unroll
    for (int r = 0; r < 4; ++r) { o01[r] = (floatx2){0.f, 0.f}; o2[r] = 0.f; }

#pragma unroll 1
    for (int nt = 0; nt < 4; ++nt) {
        // four independent chains: nt, nt+4, nt+8, nt+12
        const short8* pb0 = (const short8*)PKB + (size_t)(nt * 8) * 64 + lane;
        const short8* pb1 = pb0 + (size_t)4 * 8 * 64;
        const short8* pb2 = pb0 + (size_t)8 * 8 * 64;
        const short8* pb3 = pb0 + (size_t)12 * 8 * 64;
        const float4* ep0 = (const float4*)EPI + (size_t)nt * 128 + m;
        const float4* ep1 = ep0 + (size_t)4 * 128;
        const float4* ep2 = ep0 + (size_t)8 * 128;
        const float4* ep3 = ep0 + (size_t)12 * 128;
        floatx4 acc0 = {0.f, 0.f, 0.f, 0.f};
        floatx4 acc1 = {0.f, 0.f, 0.f, 0.f};
        floatx4 acc2 = {0.f, 0.f, 0.f, 0.f};
        floatx4 acc3 = {0.f, 0.f, 0.f, 0.f};
#pragma unroll
        for (int j = 0; j < LN; ++j) {
            short8 bf0 = pb0[j * 64];
            short8 bf1 = pb1[j * 64];
            short8 bf2 = pb2[j * 64];
            short8 bf3 = pb3[j * 64];
            float4 e0  = ep0[j * 16];
            float4 e1  = ep1[j * 16];
            float4 e2  = ep2[j * 16];
            float4 e3  = ep3[j * 16];
            acc0 = __builtin_amdgcn_mfma_f32_16x16x32_bf16(afrag[j], bf0, acc0, 0, 0, 0);
            acc1 = __builtin_amdgcn_mfma_f32_16x16x32_bf16(afrag[j], bf1, acc1, 0, 0, 0);
            acc2 = __builtin_amdgcn_mfma_f32_16x16x32_bf16(afrag[j], bf2, acc2, 0, 0, 0);
            acc3 = __builtin_amdgcn_mfma_f32_16x16x32_bf16(afrag[j], bf3, acc3, 0, 0, 0);
            floatx2 eyz0 = {e0.y, e0.z};
            floatx2 eyz1 = {e1.y, e1.z};
            floatx2 eyz2 = {e2.y, e2.z};
            floatx2 eyz3 = {e3.y, e3.z};
#pragma unroll
            for (int r = 0; r < 4; ++r) {
                float rv0 = __builtin_amdgcn_exp2f(fmaf(acc0[r], KC, e0.x));
                float rv1 = __builtin_amdgcn_exp2f(fmaf(acc1[r], KC, e1.x));
                float rv2 = __builtin_amdgcn_exp2f(fmaf(acc2[r], KC, e2.x));
                float rv3 = __builtin_amdgcn_exp2f(fmaf(acc3[r], KC, e3.x));
                o01[r] += (floatx2){rv0, rv0} * eyz0;
                o01[r] += (floatx2){rv1, rv1} * eyz1;
                o01[r] += (floatx2){rv2, rv2} * eyz2;
                o01[r] += (floatx2){rv3, rv3} * eyz3;
                o2[r]   = fmaf(rv0, e0.w, o2[r]);
                o2[r]   = fmaf(rv1, e1.w, o2[r]);
                o2[r]   = fmaf(rv2, e2.w, o2[r]);
                o2[r]   = fmaf(rv3, e3.w, o2[r]);
            }
        }
    }

    // intra-wave reduce over the 16 n-lanes (xor 1,2,4,8 stay within kq group)
    float oacc[12];
#pragma unroll
    for (int r = 0; r < 4; ++r) {
        oacc[r * 3 + 0] = o01[r].x;
        oacc[r * 3 + 1] = o01[r].y;
        oacc[r * 3 + 2] = o2[r];
    }
#pragma unroll
    for (int i = 0; i < 12; ++i) {
        oacc[i] += __shfl_xor(oacc[i], 1);
        oacc[i] += __shfl_xor(oacc[i], 2);
        oacc[i] += __shfl_xor(oacc[i], 4);
        oacc[i] += __shfl_xor(oacc[i], 8);
    }

    if (tvalid && m < OUTD) {
        float bv = bias[m];
#pragma unroll
        for (int r = 0; r < 4; ++r) {
            int row = b0 + kq * 4 + r;
            if (row < B) out[(size_t)row * OUTD + m] = oacc[r * 3 + m] + bv;
        }
    }
}

extern "C" void kernel_launch(void* const* d_in, const int* in_sizes, int n_in,
                              void* d_out, int out_size, void* d_ws, size_t ws_size,
                              hipStream_t stream) {
    // inputs: 0=x (UNUSED by reference), 1=feats, 2=centers, 3=betas, 4=W, 5=b
    const float* feats   = (const float*)d_in[1];
    const float* centers = (const float*)d_in[2];
    const float* betas   = (const float*)d_in[3];
    const float* W       = (const float*)d_in[4];
    const float* bias    = (const float*)d_in[5];
    float* out = (float*)d_out;
    int B = in_sizes[1] / (LN * FD);

    short* PKB = (short*)d_ws;                       // 65536 shorts = 128 KB
    float* EPI = (float*)((char*)d_ws + 65536 * 2);  // 8192 floats = 32 KB

    prep<<<40, 256, 0, stream>>>(centers, betas, W, PKB, EPI);

    int tiles  = (B + 15) / 16;
    int blocks = (tiles + 3) / 4;
    rbf_mfma<<<blocks, 256, 0, stream>>>(feats, PKB, EPI, bias, out, B);
}

// Round 11
// 142.585 us; speedup vs baseline: 1.5349x; 1.3856x over previous
//
#include <hip/hip_runtime.h>
#include <math.h>

#define LN 8      // layers
#define NRBF 256
#define FD 16
#define OUTD 3
#define KC (-0.72134752044f)   // -0.5 * log2(e)

typedef __attribute__((ext_vector_type(8))) short short8;   // 8 x bf16
typedef __attribute__((ext_vector_type(4))) float floatx4;
typedef __attribute__((ext_vector_type(2))) float floatx2;

__device__ __forceinline__ short f2bf(float f) {
    unsigned u = __builtin_bit_cast(unsigned, f);
    u += 0x7fffu + ((u >> 16) & 1u);          // RNE
    return (short)(u >> 16);
}

// Workspace (j-OUTER layouts so per-j slices are contiguous):
//   PKB: short8[(j*16+nt)*64 + lane]  (128 KB; 16 KB per j)  B-fragments:
//        n = nt*16+(lane&15), k = (lane>>4)*8+e, m=k>>1 -> {A, -2*A*C}
//   EPI: float4[(j*16+nt)*16 + l]    (32 KB; 4 KB per j)  {KC*t3prefix, w0, w1, w2}

__global__ __launch_bounds__(256) void prep(
    const float* __restrict__ centers, const float* __restrict__ betas,
    const float* __restrict__ W, short* __restrict__ PKB, float* __restrict__ EPI)
{
    __shared__ float ls[LN * 32];
    int blk = blockIdx.x;
    int tid = threadIdx.x;
    if (blk < 32) {
        int t = blk * 256 + tid;           // t = j*1024 + nt*64 + lane (linear!)
        int lane = t & 63;
        int nt   = (t >> 6) & 15;
        int j    = t >> 10;
        int n    = nt * 16 + (lane & 15);
        int kq   = lane >> 4;
        size_t base = ((size_t)(j * NRBF + n)) * FD + kq * 4;
        float4 bq = *(const float4*)(betas + base);
        float4 cq = *(const float4*)(centers + base);
        float a0 = __expf(bq.x), a1 = __expf(bq.y), a2 = __expf(bq.z), a3 = __expf(bq.w);
        short8 v;
        v[0] = f2bf(a0); v[1] = f2bf(-2.0f * a0 * cq.x);
        v[2] = f2bf(a1); v[3] = f2bf(-2.0f * a1 * cq.y);
        v[4] = f2bf(a2); v[5] = f2bf(-2.0f * a2 * cq.z);
        v[6] = f2bf(a3); v[7] = f2bf(-2.0f * a3 * cq.w);
        *((short8*)(PKB + (size_t)t * 8)) = v;
    } else {
        int jj = tid >> 5;                  // 0..7
        int nl = tid & 31;
        int n  = (blk - 32) * 32 + nl;
        const float* bp = betas   + ((size_t)(jj * NRBF + n)) * FD;
        const float* cp = centers + ((size_t)(jj * NRBF + n)) * FD;
        float s = 0.f;
#pragma unroll
        for (int q = 0; q < 4; ++q) {
            float4 bq = *(const float4*)(bp + q * 4);
            float4 cq = *(const float4*)(cp + q * 4);
            s = fmaf(__expf(bq.x) * cq.x, cq.x, s);
            s = fmaf(__expf(bq.y) * cq.y, cq.y, s);
            s = fmaf(__expf(bq.z) * cq.z, cq.z, s);
            s = fmaf(__expf(bq.w) * cq.w, cq.w, s);
        }
        ls[jj * 32 + nl] = s;
        __syncthreads();
        float t3 = 0.f;
        for (int j2 = 0; j2 <= jj; ++j2) t3 += ls[j2 * 32 + nl];
        float4 e;
        e.x = KC * t3;
        e.y = W[0 * (LN * NRBF) + jj * NRBF + n];
        e.z = W[1 * (LN * NRBF) + jj * NRBF + n];
        e.w = W[2 * (LN * NRBF) + jj * NRBF + n];
        int nt = n >> 4, l = n & 15;
        ((float4*)EPI)[(jj * 16 + nt) * 16 + l] = e;
    }
}

// j-OUTER / nt-INNER: each wave owns one 16-sample tile and keeps all 16
// nt-accumulators live (prefix chain is per-nt across j). Per j-step:
// 16 independent MFMAs + 64 independent exps -- no load on any dep chain.
// Per-j PKB/EPI slices (16+4 KB) double-buffered in LDS, staged one j ahead
// cooperatively via global_load_lds(16B); 8 barriers total.
__global__ __launch_bounds__(256, 3) void rbf_mfma(
    const float* __restrict__ feats, const short* __restrict__ PKB,
    const float* __restrict__ EPI, const float* __restrict__ bias,
    float* __restrict__ out, int B)
{
    __shared__ short8 pk_s[2][16 * 64];   // 2 x 16 KB
    __shared__ float4 ep_s[2][16 * 16];   // 2 x 4 KB

    int tid  = threadIdx.x;
    int lane = tid & 63;
    int w    = tid >> 6;
    int ntile_total = (B + 15) >> 4;
    int tile = blockIdx.x * 4 + w;
    bool tvalid = (tile < ntile_total);
    if (!tvalid) tile = ntile_total - 1;   // duplicate work, identical values
    int b0 = tile * 16;
    int m  = lane & 15;
    int kq = lane >> 4;

    // A-fragments: lane holds sample b0+m, k-range kq*8.. of each layer
    int brow = b0 + m; if (brow >= B) brow = B - 1;
    const float* xrow = feats + (size_t)brow * (LN * FD) + kq * 4;
    short8 afrag[LN];
#pragma unroll
    for (int j = 0; j < LN; ++j) {
        float4 x = *((const float4*)(xrow + j * FD));
        short8 f;
        f[0] = f2bf(x.x * x.x); f[1] = f2bf(x.x);
        f[2] = f2bf(x.y * x.y); f[3] = f2bf(x.y);
        f[4] = f2bf(x.z * x.z); f[5] = f2bf(x.z);
        f[6] = f2bf(x.w * x.w); f[7] = f2bf(x.w);
        afrag[j] = f;
    }

#define STAGE(buf, jv)                                                          \
    do {                                                                        \
        _Pragma("unroll")                                                       \
        for (int i = 0; i < 4; ++i) {                                           \
            const short* gp = PKB + ((size_t)(jv) * 1024 + (w * 4 + i) * 64 + lane) * 8; \
            __builtin_amdgcn_global_load_lds(                                   \
                (const __attribute__((address_space(1))) void*)gp,              \
                (__attribute__((address_space(3))) void*)&pk_s[buf][(w * 4 + i) * 64], \
                16, 0, 0);                                                      \
        }                                                                       \
        const float* ge = EPI + ((size_t)(jv) * 256 + w * 64 + lane) * 4;       \
        __builtin_amdgcn_global_load_lds(                                       \
            (const __attribute__((address_space(1))) void*)ge,                  \
            (__attribute__((address_space(3))) void*)&ep_s[buf][w * 64],        \
            16, 0, 0);                                                          \
    } while (0)

    floatx4 acc[16];
#pragma unroll
    for (int nt = 0; nt < 16; ++nt) acc[nt] = (floatx4){0.f, 0.f, 0.f, 0.f};

    floatx2 o01[4];
    float   o2[4];
#pragma unroll
    for (int r = 0; r < 4; ++r) { o01[r] = (floatx2){0.f, 0.f}; o2[r] = 0.f; }

    STAGE(0, 0);
    __syncthreads();

#pragma unroll
    for (int j = 0; j < LN; ++j) {
        int cur = j & 1;
        if (j < LN - 1) STAGE(cur ^ 1, j + 1);

        // ---- MFMA phase: 16 independent prefix updates ----
#pragma unroll
        for (int nt = 0; nt < 16; ++nt) {
            short8 bf = pk_s[cur][nt * 64 + lane];
            acc[nt] = __builtin_amdgcn_mfma_f32_16x16x32_bf16(afrag[j], bf, acc[nt], 0, 0, 0);
        }

        // ---- VALU phase: 64 independent exps + epilogue ----
#pragma unroll
        for (int nt = 0; nt < 16; ++nt) {
            float4 e = ep_s[cur][nt * 16 + m];
            floatx2 eyz = {e.y, e.z};
#pragma unroll
            for (int r = 0; r < 4; ++r) {
                float rv = __builtin_amdgcn_exp2f(fmaf(acc[nt][r], KC, e.x));
                o01[r] += (floatx2){rv, rv} * eyz;
                o2[r]   = fmaf(rv, e.w, o2[r]);
            }
        }
        __syncthreads();   // compute >> staging latency, drain is cheap
    }
#undef STAGE

    // intra-wave reduce over the 16 n-lanes (xor 1,2,4,8 stay within kq group)
    float oacc[12];
#pragma unroll
    for (int r = 0; r < 4; ++r) {
        oacc[r * 3 + 0] = o01[r].x;
        oacc[r * 3 + 1] = o01[r].y;
        oacc[r * 3 + 2] = o2[r];
    }
#pragma unroll
    for (int i = 0; i < 12; ++i) {
        oacc[i] += __shfl_xor(oacc[i], 1);
        oacc[i] += __shfl_xor(oacc[i], 2);
        oacc[i] += __shfl_xor(oacc[i], 4);
        oacc[i] += __shfl_xor(oacc[i], 8);
    }

    if (tvalid && m < OUTD) {
        float bv = bias[m];
#pragma unroll
        for (int r = 0; r < 4; ++r) {
            int row = b0 + kq * 4 + r;
            if (row < B) out[(size_t)row * OUTD + m] = oacc[r * 3 + m] + bv;
        }
    }
}

extern "C" void kernel_launch(void* const* d_in, const int* in_sizes, int n_in,
                              void* d_out, int out_size, void* d_ws, size_t ws_size,
                              hipStream_t stream) {
    // inputs: 0=x (UNUSED by reference), 1=feats, 2=centers, 3=betas, 4=W, 5=b
    const float* feats   = (const float*)d_in[1];
    const float* centers = (const float*)d_in[2];
    const float* betas   = (const float*)d_in[3];
    const float* W       = (const float*)d_in[4];
    const float* bias    = (const float*)d_in[5];
    float* out = (float*)d_out;
    int B = in_sizes[1] / (LN * FD);

    short* PKB = (short*)d_ws;                       // 65536 shorts = 128 KB
    float* EPI = (float*)((char*)d_ws + 65536 * 2);  // 8192 floats = 32 KB

    prep<<<40, 256, 0, stream>>>(centers, betas, W, PKB, EPI);

    int tiles  = (B + 15) / 16;
    int blocks = (tiles + 3) / 4;
    rbf_mfma<<<blocks, 256, 0, stream>>>(feats, PKB, EPI, bias, out, B);
}